// Round 1
// baseline (48.174 us; speedup 1.0000x reference)
//
#include <hip/hip_runtime.h>
#include <math.h>

#define EARLY 0.7f
#define LATE  1.5f
#define BLOCKS 2048
#define THREADS 256

// Stage 1: per-block partial sums of weighted squared diff.
__global__ __launch_bounds__(THREADS) void rmse_partial_kernel(
    const float4* __restrict__ inputs,
    const float4* __restrict__ targets,
    float* __restrict__ partials,
    int nrows) {
    int tid = blockIdx.x * blockDim.x + threadIdx.x;
    int stride = gridDim.x * blockDim.x;

    float acc = 0.0f;
    for (int r = tid; r < nrows; r += stride) {
        float4 a = inputs[r];
        float4 b = targets[r];
        float d0 = b.x - a.x;
        float d1 = b.y - a.y;
        float d2 = b.z - a.z;
        float d3 = b.w - a.w;
        float w0 = (d0 >= 0.0f) ? EARLY : LATE;
        acc += d0 * d0 * w0 + d1 * d1 + d2 * d2 + d3 * d3;
    }

    // Wave-64 butterfly reduce.
    #pragma unroll
    for (int off = 32; off > 0; off >>= 1)
        acc += __shfl_down(acc, off, 64);

    __shared__ float smem[THREADS / 64];
    int wave = threadIdx.x >> 6;
    if ((threadIdx.x & 63) == 0) smem[wave] = acc;
    __syncthreads();

    if (threadIdx.x == 0) {
        float s = 0.0f;
        #pragma unroll
        for (int w = 0; w < THREADS / 64; ++w) s += smem[w];
        partials[blockIdx.x] = s;
    }
}

// Stage 2: reduce the per-block partials, apply mean + sqrt.
__global__ __launch_bounds__(THREADS) void rmse_final_kernel(
    const float* __restrict__ partials,
    int n,
    float* __restrict__ out,
    float inv_count) {
    float acc = 0.0f;
    for (int i = threadIdx.x; i < n; i += blockDim.x)
        acc += partials[i];

    #pragma unroll
    for (int off = 32; off > 0; off >>= 1)
        acc += __shfl_down(acc, off, 64);

    __shared__ float smem[THREADS / 64];
    int wave = threadIdx.x >> 6;
    if ((threadIdx.x & 63) == 0) smem[wave] = acc;
    __syncthreads();

    if (threadIdx.x == 0) {
        float s = 0.0f;
        #pragma unroll
        for (int w = 0; w < THREADS / 64; ++w) s += smem[w];
        out[0] = sqrtf(s * inv_count);
    }
}

extern "C" void kernel_launch(void* const* d_in, const int* in_sizes, int n_in,
                              void* d_out, int out_size, void* d_ws, size_t ws_size,
                              hipStream_t stream) {
    const float4* inputs  = (const float4*)d_in[0];
    const float4* targets = (const float4*)d_in[1];
    float* out = (float*)d_out;
    float* partials = (float*)d_ws;

    const int total = in_sizes[0];          // N * D elements
    const int nrows = total / 4;            // D == 4 -> one float4 per row

    rmse_partial_kernel<<<BLOCKS, THREADS, 0, stream>>>(inputs, targets, partials, nrows);

    const float inv_count = 1.0f / (float)total;
    rmse_final_kernel<<<1, THREADS, 0, stream>>>(partials, BLOCKS, out, inv_count);
}